// Round 1
// baseline (320.782 us; speedup 1.0000x reference)
//
#include <hip/hip_runtime.h>

// TransposedLocallyConnected2D: out[b,o,l] = sum_d u[b,d,l] * W[d,l,o] + bias[o,l]
//   B=64, C=64, H=W=32, OC=128, KH=KW=3, PAD=1, OH=OW=32, L=1024, D=576
// One block per output location l: 64x128 GEMM with K=576, chunked Kc=36.

#define B_    64
#define C_    64
#define OC_   128
#define L_    1024
#define KC    36     // 4 channels * 9 taps per chunk
#define NCH   16     // 64 channels / 4
#define USTR  68     // 64 + 4 pad (keeps 16B alignment: 68*4=272=17*16)

__global__ __launch_bounds__(256, 4)
void lc2d_kernel(const float* __restrict__ x,
                 const float* __restrict__ w,
                 const float* __restrict__ bias,
                 float* __restrict__ out)
{
    __shared__ float Us[KC][USTR];   // [k][b]
    __shared__ float Ws[KC][OC_];    // [k][o]

    const int blk = blockIdx.x;
    // Bijective XCD swizzle: XCD (blk%8) owns contiguous l-range so the 16
    // blocks sharing each 64B out-line hit the same L2 close in time.
    const int l  = ((blk & 7) << 7) | (blk >> 3);
    const int oh = l >> 5;
    const int ow = l & 31;
    const int tid = threadIdx.x;
    const int tx = tid & 15;   // -> o = tx*4 + {0..3} and tx*4+64+{0..3}
    const int ty = tid >> 4;   // -> b = ty*4 + {0..3}
    const int sb = tid >> 2;   // staging: batch 0..63
    const int sc = tid & 3;    // staging: channel-in-chunk 0..3

    float acc[4][8];
    #pragma unroll
    for (int i = 0; i < 4; ++i)
        #pragma unroll
        for (int j = 0; j < 8; ++j)
            acc[i][j] = 0.f;

    for (int ch = 0; ch < NCH; ++ch) {
        const int c0 = ch * 4;

        // ---- stage Us[k][b]: k = sc*9 + ii*3 + jj, u = x[b, c0+sc, oh+ii-1, ow+jj-1]
        const float* xb = x + ((size_t)(sb * C_ + c0 + sc) << 10); // *32*32
        #pragma unroll
        for (int ii = 0; ii < 3; ++ii) {
            const int y = oh + ii - 1;
            const bool yok = ((unsigned)y < 32u);   // block-uniform
            #pragma unroll
            for (int jj = 0; jj < 3; ++jj) {
                const int z = ow + jj - 1;
                float v = 0.f;
                if (yok && ((unsigned)z < 32u))     // block-uniform
                    v = xb[(y << 5) + z];
                Us[sc * 9 + ii * 3 + jj][sb] = v;
            }
        }

        // ---- stage Ws[k][o]: rows d = c0*9 + kk, coalesced float4
        const int dbase = c0 * 9;
        #pragma unroll
        for (int it = 0; it < 5; ++it) {
            const int idx = tid + it * 256;
            if (idx < KC * 32) {
                const int kk = idx >> 5;
                const int o4 = idx & 31;
                const float4 v = *reinterpret_cast<const float4*>(
                    w + (((size_t)(dbase + kk) * L_ + l) * OC_ + o4 * 4));
                *reinterpret_cast<float4*>(&Ws[kk][o4 * 4]) = v;
            }
        }

        __syncthreads();

        // ---- compute: 3x ds_read_b128 + 32 FMA per k-step
        #pragma unroll 6
        for (int kk = 0; kk < KC; ++kk) {
            const float4 ub = *reinterpret_cast<const float4*>(&Us[kk][ty * 4]);
            const float4 wa = *reinterpret_cast<const float4*>(&Ws[kk][tx * 4]);
            const float4 wb = *reinterpret_cast<const float4*>(&Ws[kk][tx * 4 + 64]);
            const float u[4]  = {ub.x, ub.y, ub.z, ub.w};
            const float a[4]  = {wa.x, wa.y, wa.z, wa.w};
            const float b2[4] = {wb.x, wb.y, wb.z, wb.w};
            #pragma unroll
            for (int bi = 0; bi < 4; ++bi) {
                #pragma unroll
                for (int oi = 0; oi < 4; ++oi) {
                    acc[bi][oi]     += u[bi] * a[oi];
                    acc[bi][4 + oi] += u[bi] * b2[oi];
                }
            }
        }

        __syncthreads();
    }

    // ---- epilogue: out[b,o,l] = acc + bias[o,l]
    float bs[8];
    #pragma unroll
    for (int oi = 0; oi < 4; ++oi) {
        bs[oi]     = bias[((tx * 4 + oi) << 10) + l];
        bs[4 + oi] = bias[((tx * 4 + 64 + oi) << 10) + l];
    }
    #pragma unroll
    for (int bi = 0; bi < 4; ++bi) {
        const int b = ty * 4 + bi;
        #pragma unroll
        for (int oi = 0; oi < 4; ++oi) {
            out[((b * OC_ + tx * 4 + oi) << 10) + l]      = acc[bi][oi]     + bs[oi];
            out[((b * OC_ + tx * 4 + 64 + oi) << 10) + l] = acc[bi][4 + oi] + bs[4 + oi];
        }
    }
}

extern "C" void kernel_launch(void* const* d_in, const int* in_sizes, int n_in,
                              void* d_out, int out_size, void* d_ws, size_t ws_size,
                              hipStream_t stream) {
    const float* x    = (const float*)d_in[0];
    const float* w    = (const float*)d_in[1];
    const float* bias = (const float*)d_in[2];
    float* out        = (float*)d_out;
    lc2d_kernel<<<dim3(1024), dim3(256), 0, stream>>>(x, w, bias, out);
}

// Round 4
// 277.618 us; speedup vs baseline: 1.1555x; 1.1555x over previous
//
#include <hip/hip_runtime.h>
#include <hip/hip_bf16.h>

// TransposedLocallyConnected2D: out[b,o,l] = sum_d U[b,d,l] * W[d,l,o] + bias[o,l]
//   B=64, C=64, OC=128, L=1024, D=576 (d = c*9 + ii*3 + jj). Per-l 64x128x576 GEMM.
//
// Single MFMA kernel, no exotic primitives:
//  - block per l (XCD-swizzled). Two 288-d chunks; per chunk: U->LDS->afr[9] regs.
//  - W k-tiles (32 d x 128 o) loaded f32 via coalesced global_load_dwordx2,
//    cvt to bf16 in-register, staged with plain ds_write_b128 into a
//    [128 o][4 slot][16B] tile; slot XOR-swizzled by the SAME formula on
//    write (s ^ ((o>>1)&3)) and read (g ^ ((o>>1)&3)) -> read returns slot g.
//  - 8x mfma_f32_16x16x32_bf16 per tile per wave; double-buffered (2x8KB),
//    issue-early/write-late register prefetch, one barrier per tile.
//  - WSPATH: ws[l][o][b] full-line stores + out_kernel transpose (+bias).
//    Fallback (ws too small): direct scatter stores (+bias), correct but slower.

typedef __attribute__((ext_vector_type(8))) short bf16x8;
typedef __attribute__((ext_vector_type(4))) float f32x4;
typedef __attribute__((ext_vector_type(2))) float f32x2;
typedef __attribute__((ext_vector_type(8))) unsigned short us8;

#define UROW 296   // U chunk row stride in bf16: 288 data + 8 pad (592B = 37*16)

__device__ __forceinline__ unsigned short f2bf(float f) {
    union { __hip_bfloat16 h; unsigned short u; } cv;
    cv.h = __float2bfloat16(f);
    return cv.u;
}

struct WTile { f32x2 v[8]; };

// load k-tile kb (rows d = kb*32 + s*8 + e, cols [oA, oA+1]) into regs
__device__ __forceinline__ void wload(const float* __restrict__ w, int l, int kb,
                                      int s, int oA, WTile& t) {
    const float* wp = w + ((size_t)(kb * 32 + s * 8) * 1024 + (size_t)l) * 128 + oA;
    #pragma unroll
    for (int e = 0; e < 8; ++e)
        t.v[e] = *(const f32x2*)(wp + (size_t)e * 131072);   // d-stride = 1024*128
}

// cvt + store both staged rows (o = oA, oA+1), swizzled slot position
__device__ __forceinline__ void wstore(char* buf, int wrA, const WTile& t) {
    us8 a, b;
    #pragma unroll
    for (int e = 0; e < 8; ++e) { a[e] = f2bf(t.v[e][0]); b[e] = f2bf(t.v[e][1]); }
    *(us8*)(buf + wrA)      = a;
    *(us8*)(buf + wrA + 64) = b;
}

template <bool WSPATH>
__global__ __launch_bounds__(256, 4)
void mfma_kernel(const float* __restrict__ x,
                 const float* __restrict__ w,
                 const float* __restrict__ bias,
                 float* __restrict__ wsout,
                 float* __restrict__ out)
{
    __shared__ unsigned short smem[64 * UROW];   // 37888 B; W dbuf overlays [0,16384)

    const int blk  = blockIdx.x;
    const int l    = ((blk & 7) << 7) | (blk >> 3);   // bijective XCD swizzle
    const int oh   = l >> 5, ow = l & 31;
    const int tid  = threadIdx.x;
    const int lane = tid & 63;
    const int wv   = tid >> 6;      // wave id; also W staging d-slot s
    const int r    = lane & 15;
    const int g    = lane >> 4;

    // staging addresses: thread t owns rows d=32kb+wv*8+e, cols oA,oA+1
    const int oA   = (tid & 63) * 2;
    const int wrA  = oA * 64 + ((wv ^ (tid & 3)) << 4);        // f(o)=(o>>1)&3 = tid&3
    // read address: row o = nt*16 + r, slot g at position g ^ ((o>>1)&3)
    const int rdb  = r * 64 + ((g ^ ((r >> 1) & 3)) << 4);

    char* lds = (char*)smem;

    f32x4 acc[8];
    #pragma unroll
    for (int n = 0; n < 8; ++n) acc[n] = (f32x4){0.f, 0.f, 0.f, 0.f};

    #pragma unroll
    for (int c2 = 0; c2 < 2; ++c2) {
        // ---- stage U chunk c2 (d in [288*c2, 288*c2+288)) as bf16 rows
        {
            const int sb  = tid & 63;
            const int scg = tid >> 6;
            #pragma unroll
            for (int cl = 0; cl < 8; ++cl) {
                const int c = c2 * 32 + scg * 8 + cl;
                const float* xp = x + ((size_t)(sb * 64 + c) << 10);
                unsigned short* ur = smem + sb * UROW + (scg * 8 + cl) * 9;
                #pragma unroll
                for (int ii = 0; ii < 3; ++ii) {
                    const int y = oh + ii - 1;
                    const bool yok = (unsigned)y < 32u;
                    #pragma unroll
                    for (int jj = 0; jj < 3; ++jj) {
                        const int z = ow + jj - 1;
                        float v = (yok && ((unsigned)z < 32u)) ? xp[(y << 5) + z] : 0.f;
                        ur[ii * 3 + jj] = f2bf(v);
                    }
                }
            }
        }
        __syncthreads();

        // ---- A-fragments for this chunk: lane (r,g) row b=16wv+r, k=32kbl+8g+i
        bf16x8 afr[9];
        {
            const unsigned short* Ur = smem + (16 * wv + r) * UROW;
            #pragma unroll
            for (int kbl = 0; kbl < 9; ++kbl)
                afr[kbl] = *(const bf16x8*)(Ur + kbl * 32 + g * 8);
        }
        __syncthreads();   // afr reads done before W staging overwrites LDS

        // ---- prime first W tile of the chunk into buf0
        {
            WTile t;
            wload(w, l, c2 * 9, wv, oA, t);
            wstore(lds + wrA, 0, t);
        }
        __syncthreads();

        // ---- 9 k-tiles, double-buffered, issue-early / write-late
        #pragma unroll
        for (int kt = 0; kt < 9; ++kt) {
            const int cur = kt & 1;
            WTile t;
            if (kt < 8)
                wload(w, l, c2 * 9 + kt + 1, wv, oA, t);   // prefetch into regs

            const char* bufp = lds + (cur << 13) + rdb;
            #pragma unroll
            for (int nt = 0; nt < 8; ++nt) {
                const bf16x8 bfr = *(const bf16x8*)(bufp + nt * 1024);
                acc[nt] = __builtin_amdgcn_mfma_f32_16x16x32_bf16(afr[kt], bfr, acc[nt], 0, 0, 0);
            }

            if (kt < 8)
                wstore(lds + ((cur ^ 1) << 13) + wrA, 0, t);
            __syncthreads();
        }
        // last barrier also protects the U restage (c2=1) overwriting W buffers
    }

    // ---- epilogue: D elem q -> b = 16wv + 4g + q, o = nt*16 + r (m89 C/D layout)
    if (WSPATH) {
        float* wsp = wsout + ((size_t)l << 13) + wv * 16 + g * 4;
        #pragma unroll
        for (int nt = 0; nt < 8; ++nt)
            *(f32x4*)(wsp + ((nt * 16 + r) << 6)) = acc[nt];
    } else {
        #pragma unroll
        for (int nt = 0; nt < 8; ++nt) {
            const int o = nt * 16 + r;
            const float bz = bias[(o << 10) + l];
            #pragma unroll
            for (int q = 0; q < 4; ++q) {
                const int b = wv * 16 + g * 4 + q;
                out[((size_t)(b * 128 + o) << 10) + l] = acc[nt][q] + bz;
            }
        }
    }
}

// ws[l][o][b] -> out[b][o][l] (+bias), tiles [32 l][16 o][16 b]
__global__ __launch_bounds__(256, 4)
void out_kernel(const float* __restrict__ ws,
                const float* __restrict__ bias,
                float* __restrict__ out)
{
    __shared__ float Ls[32 * 16 * 16];
    const int blk = blockIdx.x;
    const int b0 = (blk & 3) * 16;
    const int o0 = ((blk >> 2) & 7) * 16;
    const int l0 = (blk >> 5) * 32;
    const int t  = threadIdx.x;

    const int b4  = (t & 3) * 4;
    const int o   = (t >> 2) & 15;
    const int lr0 = t >> 6;
    #pragma unroll
    for (int p = 0; p < 8; ++p) {
        const int lr = lr0 + 4 * p;
        const f32x4 v = *(const f32x4*)(ws + (size_t)(l0 + lr) * 8192 + (o0 + o) * 64 + b0 + b4);
        *(f32x4*)(&Ls[(lr * 16 + o) * 16 + b4]) = v;
    }
    __syncthreads();

    const int lq = (t & 7) * 4;
    #pragma unroll
    for (int p = 0; p < 8; ++p) {
        const int row   = p * 32 + (t >> 3);
        const int o_loc = row >> 4;
        const int b_loc = row & 15;
        f32x4 v;
        #pragma unroll
        for (int q = 0; q < 4; ++q)
            v[q] = Ls[((lq + q) * 16 + o_loc) * 16 + b_loc];
        const f32x4 bz = *(const f32x4*)(bias + (o0 + o_loc) * 1024 + l0 + lq);
        v += bz;
        *(f32x4*)(out + ((size_t)((b0 + b_loc) * 128) + o0 + o_loc) * 1024 + l0 + lq) = v;
    }
}

extern "C" void kernel_launch(void* const* d_in, const int* in_sizes, int n_in,
                              void* d_out, int out_size, void* d_ws, size_t ws_size,
                              hipStream_t stream) {
    const float* x    = (const float*)d_in[0];
    const float* w    = (const float*)d_in[1];
    const float* bias = (const float*)d_in[2];
    float* out        = (float*)d_out;

    const size_t WSO_BYTES = 64ull * 128 * 1024 * 4;   // 33,554,432

    if (d_ws && ws_size >= WSO_BYTES) {
        float* wso = (float*)d_ws;
        mfma_kernel<true><<<dim3(1024), dim3(256), 0, stream>>>(x, w, bias, wso, out);
        out_kernel<<<dim3(1024), dim3(256), 0, stream>>>(wso, bias, out);
    } else {
        mfma_kernel<false><<<dim3(1024), dim3(256), 0, stream>>>(x, w, bias, nullptr, out);
    }
}